// Round 4
// baseline (733.179 us; speedup 1.0000x reference)
//
#include <hip/hip_runtime.h>
#include <math.h>

#define HWN   6400      // 80*80
#define IMW   80
#define NCH   21
#define RAD   15
#define NTAP  (2*RAD+1) // 31
#define NF    56        // monomials of degree <=5 in 3 vars
#define NTH   640       // 10 waves -> VGPR cap ~168 (3 waves on busiest SIMD)
#define NPIX  10        // pixels per thread (640*10 = 6400, exact)
#define NITER 5
#define NWAVE (NTH/64)  // 10
#define WLEN  (NPIX + 2*RAD)  // 40-elem register sliding window

// Gaussian taps exp(-d^2/18), d = j-15, as compile-time constants; unrolled
// MACs encode them as VOP2 32-bit literals (zero VGPR, zero LDS cost).
constexpr float TK[NTAP] = {
    3.7266532e-06f, 1.8664500e-05f, 8.3648600e-05f, 3.3546262e-04f,
    1.2038700e-03f, 3.8660700e-03f, 1.1108997e-02f, 2.8565540e-02f,
    6.5728700e-02f, 1.3533528e-01f, 2.4936889e-01f, 4.1111229e-01f,
    6.0653066e-01f, 8.0073740e-01f, 9.4595947e-01f, 1.0000000e+00f,
    9.4595947e-01f, 8.0073740e-01f, 6.0653066e-01f, 4.1111229e-01f,
    2.4936889e-01f, 1.3533528e-01f, 6.5728700e-02f, 2.8565540e-02f,
    1.1108997e-02f, 3.8660700e-03f, 1.2038700e-03f, 3.3546262e-04f,
    8.3648600e-05f, 1.8664500e-05f, 3.7266532e-06f
};

// Full-wave (64-lane) f32 sum on the VALU pipe via DPP (no LDS traffic).
// row_shr 1/2/4/8 (rows of 16), row_bcast15 (row_mask 0xa), row_bcast31
// (row_mask 0xc). old=0 + bound_ctrl => invalid/masked lanes contribute 0.
// Full sum lands in lane 63.
__device__ __forceinline__ float wave_red_sum(float v) {
    v += __int_as_float(__builtin_amdgcn_update_dpp(0, __float_as_int(v), 0x111, 0xf, 0xf, true));
    v += __int_as_float(__builtin_amdgcn_update_dpp(0, __float_as_int(v), 0x112, 0xf, 0xf, true));
    v += __int_as_float(__builtin_amdgcn_update_dpp(0, __float_as_int(v), 0x114, 0xf, 0xf, true));
    v += __int_as_float(__builtin_amdgcn_update_dpp(0, __float_as_int(v), 0x118, 0xf, 0xf, true));
    v += __int_as_float(__builtin_amdgcn_update_dpp(0, __float_as_int(v), 0x142, 0xa, 0xf, true));
    v += __int_as_float(__builtin_amdgcn_update_dpp(0, __float_as_int(v), 0x143, 0xc, 0xf, true));
    return v;  // lane 63 holds the full 64-lane sum
}

// One block per (b,c) image; whole 5-iteration mean-field loop fused in-block.
// Spatial message: separable 1D Gaussian (radius 15, trunc err ~2e-7 rel).
// Bilateral: exp(-d2/50) = e_n*e_m*exp(f_n.f_m/25), order-5 Taylor in 56
// monomial features (rel err ~5e-9) -> two rank-56 projections.
__global__ __launch_bounds__(NTH, 1)
void crf_fused(const float* __restrict__ pred,
               const float* __restrict__ img,
               float* __restrict__ out)
{
    __shared__ float Qs[HWN];                      // current Q     (25.6 KB)
    __shared__ float Ts[HWN];                      // y-conv result (25.6 KB)
    __shared__ __align__(16) float Pw[NWAVE][NF];  // per-wave partials
    __shared__ __align__(16) float PkS[NF];        // reduced * (5*coef)
    __shared__ float CfS[NF];

    const int tid  = threadIdx.x;
    const int wid  = tid >> 6;
    const int lane = tid & 63;
    const int bc   = blockIdx.x;       // 0..41
    const int b    = bc / NCH;

    // horizontal 1x10 strip (phases A, F, output): row hr, cols hx..hx+9
    const int hr    = tid >> 3;            // 0..79
    const int hx    = (tid & 7) * NPIX;    // 0,10,..,70
    const int hbase = hr * IMW + hx;
    // vertical 10x1 strip (phase B): col vx, rows vyb..vyb+9
    const int vx  = tid % IMW;
    const int vyb = (tid / IMW) * NPIX;

    const float* predp = pred + (size_t)bc * HWN;
    const float* imgp  = img  + (size_t)b * 3 * HWN;
    float*       outp  = out  + (size_t)bc * HWN;

    if (tid < NF) {
        // enumeration order matches the evaluation loops below:
        // ar asc, then ag asc, then ab asc, with ar+ag+ab <= 5
        int f = 0; float coef = 0.0f;
        const float fact[6] = {1.f, 1.f, 2.f, 6.f, 24.f, 120.f};
        for (int ar = 0; ar <= 5; ++ar)
            for (int ag = 0; ag + ar <= 5; ++ag)
                for (int ab = 0; ab + ag + ar <= 5; ++ab) {
                    if (f == tid) {
                        int k = ar + ag + ab;
                        float p25 = 1.0f;
                        for (int j = 0; j < k; ++j) p25 *= 25.0f;
                        coef = 5.0f / (p25 * fact[ar] * fact[ag] * fact[ab]);
                    }
                    ++f;
                }
        CfS[tid] = coef;
    }

    // persistent per-pixel state on the horizontal strip
    float qv[NPIX], ev[NPIX];
    #pragma unroll
    for (int j = 0; j < NPIX; ++j) {
        int i = hbase + j;
        float r  = imgp[i];
        float g  = imgp[HWN + i];
        float bb = imgp[2 * HWN + i];
        ev[j] = expf(-(r * r + g * g + bb * bb) * 0.02f);
        float p = predp[i];
        qv[j] = p;
        Qs[i] = p;
    }
    __syncthreads();

    for (int it = 0; it < NITER; ++it) {
        // ---- A: bilateral projection partials (registers + cached global) ----
        float pacc[NF];
        #pragma unroll
        for (int f = 0; f < NF; ++f) pacc[f] = 0.0f;

        #pragma unroll
        for (int j = 0; j < NPIX; ++j) {
            int i = hbase + j;
            float r  = imgp[i];
            float g  = imgp[HWN + i];
            float bb = imgp[2 * HWN + i];
            float rp[6], gp[6], bp[6];
            rp[0] = 1.f; gp[0] = 1.f; bp[0] = 1.f;
            #pragma unroll
            for (int k = 1; k < 6; ++k) {
                rp[k] = rp[k-1] * r; gp[k] = gp[k-1] * g; bp[k] = bp[k-1] * bb;
            }
            float qe = qv[j] * ev[j];
            int f = 0;
            #pragma unroll
            for (int ar = 0; ar <= 5; ++ar) {
                float va = qe * rp[ar];
                #pragma unroll
                for (int ag = 0; ag + ar <= 5; ++ag) {
                    float vb = va * gp[ag];
                    #pragma unroll
                    for (int ab = 0; ab + ag + ar <= 5; ++ab) {
                        pacc[f] += vb * bp[ab];
                        ++f;
                    }
                }
            }
        }

        // ---- C: DPP wave-reduce (VALU pipe); lane 63 writes float4 groups ----
        // (placed before B so pacc[56] dies before the conv window registers live)
        #pragma unroll
        for (int f0 = 0; f0 < NF; f0 += 4) {
            float4 wv4;
            wv4.x = wave_red_sum(pacc[f0 + 0]);
            wv4.y = wave_red_sum(pacc[f0 + 1]);
            wv4.z = wave_red_sum(pacc[f0 + 2]);
            wv4.w = wave_red_sum(pacc[f0 + 3]);
            if (lane == 63) *(float4*)&Pw[wid][f0] = wv4;
        }

        // ---- B: y-conv, vertical strip, register sliding window ----
        {
            float wv[WLEN];
            #pragma unroll
            for (int m = 0; m < WLEN; ++m) {
                int yy = vyb - RAD + m;
                int yc = min(max(yy, 0), IMW - 1);
                float msk = ((unsigned)yy < (unsigned)IMW) ? 1.0f : 0.0f;
                wv[m] = Qs[yc * IMW + vx] * msk;   // branchless clamped load
            }
            #pragma unroll
            for (int k = 0; k < NPIX; ++k) {
                float s = 0.0f;
                #pragma unroll
                for (int j = 0; j < NTAP; ++j) s += wv[k + j] * TK[j];
                Ts[(vyb + k) * IMW + vx] = s;
            }
        }
        __syncthreads();   // Pw ready, Ts ready

        // ---- D: cross-wave reduce + fold 5*coef ----
        if (tid < NF) {
            float s = 0.0f;
            #pragma unroll
            for (int w = 0; w < NWAVE; ++w) s += Pw[w][tid];
            PkS[tid] = s * CfS[tid];
        }
        __syncthreads();   // PkS ready

        // ---- F: x-conv (register window) + bilateral apply + sigmoid ----
        float sp[NPIX];
        {
            float wv[WLEN];
            #pragma unroll
            for (int m = 0; m < WLEN; ++m) {
                int xx = hx - RAD + m;
                int xc = min(max(xx, 0), IMW - 1);
                float msk = ((unsigned)xx < (unsigned)IMW) ? 1.0f : 0.0f;
                wv[m] = Ts[hr * IMW + xc] * msk;
            }
            #pragma unroll
            for (int k = 0; k < NPIX; ++k) {
                float s = 0.0f;
                #pragma unroll
                for (int j = 0; j < NTAP; ++j) s += wv[k + j] * TK[j];
                sp[k] = s;
            }
        }
        float pk[NF];
        {
            const float4* p4 = (const float4*)PkS;   // uniform-address broadcast
            #pragma unroll
            for (int k = 0; k < NF / 4; ++k) {
                float4 t = p4[k];
                pk[4*k+0] = t.x; pk[4*k+1] = t.y; pk[4*k+2] = t.z; pk[4*k+3] = t.w;
            }
        }
        #pragma unroll
        for (int j = 0; j < NPIX; ++j) {
            int i = hbase + j;
            float r  = imgp[i];
            float g  = imgp[HWN + i];
            float bb = imgp[2 * HWN + i];
            float rp[6], gp[6], bp[6];
            rp[0] = 1.f; gp[0] = 1.f; bp[0] = 1.f;
            #pragma unroll
            for (int k = 1; k < 6; ++k) {
                rp[k] = rp[k-1] * r; gp[k] = gp[k-1] * g; bp[k] = bp[k-1] * bb;
            }
            float bi = 0.0f;
            int f = 0;
            #pragma unroll
            for (int ar = 0; ar <= 5; ++ar) {
                float va = ev[j] * rp[ar];
                #pragma unroll
                for (int ag = 0; ag + ar <= 5; ++ag) {
                    float vb = va * gp[ag];
                    #pragma unroll
                    for (int ab = 0; ab + ag + ar <= 5; ++ab) {
                        bi += (pk[f] * vb) * bp[ab];
                        ++f;
                    }
                }
            }
            float x = predp[i] - 3.0f * sp[j] - bi;
            float q = 1.0f / (1.0f + expf(-x));
            qv[j] = q;
            Qs[i] = q;
        }
        __syncthreads();   // Qs stable for next B; Ts fully consumed
    }

    #pragma unroll
    for (int j = 0; j < NPIX; ++j) outp[hbase + j] = qv[j];
}

extern "C" void kernel_launch(void* const* d_in, const int* in_sizes, int n_in,
                              void* d_out, int out_size, void* d_ws, size_t ws_size,
                              hipStream_t stream) {
    const float* pred = (const float*)d_in[0];   // [2,21,80,80]
    const float* img  = (const float*)d_in[1];   // [2,3,80,80]
    float* out = (float*)d_out;                  // [2,21,80,80]
    (void)in_sizes; (void)n_in; (void)d_ws; (void)ws_size; (void)out_size;

    crf_fused<<<dim3(2 * NCH), dim3(NTH), 0, stream>>>(pred, img, out);
}

// Round 6
// 617.204 us; speedup vs baseline: 1.1879x; 1.1879x over previous
//
#include <hip/hip_runtime.h>
#include <math.h>

#define HWN   6400      // 80*80
#define IMW   80
#define NCH   21
#define RAD   15
#define NTAP  (2*RAD+1) // 31
#define NF    35        // monomials of degree <=4 in 3 vars (Taylor order 4)
#define NFP   36        // padded to multiple of 4 for float4 LDS ops
#define NTH   640       // 10 waves; 3/3/2/2 per SIMD -> VGPR cap ~168
#define NPIX  10        // pixels per thread (640*10 = 6400, exact)
#define NITER 5
#define NWAVE (NTH/64)  // 10
#define WLEN  (NPIX + 2*RAD)  // 40-elem register sliding window

// Gaussian taps exp(-d^2/18), d = j-15; compile-time constants -> the fully
// unrolled MACs encode each tap as a VOP2 32-bit literal (zero VGPR cost).
constexpr float TK[NTAP] = {
    3.7266532e-06f, 1.8664500e-05f, 8.3648600e-05f, 3.3546262e-04f,
    1.2038700e-03f, 3.8660700e-03f, 1.1108997e-02f, 2.8565540e-02f,
    6.5728700e-02f, 1.3533528e-01f, 2.4936889e-01f, 4.1111229e-01f,
    6.0653066e-01f, 8.0073740e-01f, 9.4595947e-01f, 1.0000000e+00f,
    9.4595947e-01f, 8.0073740e-01f, 6.0653066e-01f, 4.1111229e-01f,
    2.4936889e-01f, 1.3533528e-01f, 6.5728700e-02f, 2.8565540e-02f,
    1.1108997e-02f, 3.8660700e-03f, 1.2038700e-03f, 3.3546262e-04f,
    8.3648600e-05f, 1.8664500e-05f, 3.7266532e-06f
};

// Monomial exponents (r,g,b) for the 35 features, flat order:
// ar asc, then ag asc, then ab asc, with ar+ag+ab <= 4.
// Indexed with COMPILE-TIME f inside fully-unrolled loops -> folds to
// constant register indices (this is the scratch-spill fix; Rule #20).
constexpr int AR[NF] = {0,0,0,0,0, 0,0,0,0, 0,0,0, 0,0, 0,
                        1,1,1,1, 1,1,1, 1,1, 1,
                        2,2,2, 2,2, 2,
                        3,3, 3,
                        4};
constexpr int AG[NF] = {0,0,0,0,0, 1,1,1,1, 2,2,2, 3,3, 4,
                        0,0,0,0, 1,1,1, 2,2, 3,
                        0,0,0, 1,1, 2,
                        0,0, 1,
                        0};
constexpr int AB[NF] = {0,1,2,3,4, 0,1,2,3, 0,1,2, 0,1, 0,
                        0,1,2,3, 0,1,2, 0,1, 0,
                        0,1,2, 0,1, 0,
                        0,1, 0,
                        0};

// Full-wave (64-lane) f32 sum on the VALU pipe via DPP (no LDS traffic).
// row_shr 1/2/4/8 (rows of 16), row_bcast15 (row_mask 0xa), row_bcast31
// (row_mask 0xc). old=0 + bound_ctrl => invalid/masked lanes contribute 0.
// Full sum lands in lane 63.
__device__ __forceinline__ float wave_red_sum(float v) {
    v += __int_as_float(__builtin_amdgcn_update_dpp(0, __float_as_int(v), 0x111, 0xf, 0xf, true));
    v += __int_as_float(__builtin_amdgcn_update_dpp(0, __float_as_int(v), 0x112, 0xf, 0xf, true));
    v += __int_as_float(__builtin_amdgcn_update_dpp(0, __float_as_int(v), 0x114, 0xf, 0xf, true));
    v += __int_as_float(__builtin_amdgcn_update_dpp(0, __float_as_int(v), 0x118, 0xf, 0xf, true));
    v += __int_as_float(__builtin_amdgcn_update_dpp(0, __float_as_int(v), 0x142, 0xa, 0xf, true));
    v += __int_as_float(__builtin_amdgcn_update_dpp(0, __float_as_int(v), 0x143, 0xc, 0xf, true));
    return v;  // lane 63 holds the full 64-lane sum
}

// One block per (b,c) image; whole 5-iteration mean-field loop fused in-block.
// Spatial message: separable 1D Gaussian (radius 15, trunc err ~2e-7 rel).
// Bilateral: exp(-d2/50) = e_n*e_m*exp(f_n.f_m/25), order-4 Taylor in 35
// monomial features (rel err ~2e-7) -> two rank-35 projections.
__global__ __launch_bounds__(NTH, 3)
void crf_fused(const float* __restrict__ pred,
               const float* __restrict__ img,
               float* __restrict__ out)
{
    __shared__ float Qs[HWN];                       // current Q     (25.6 KB)
    __shared__ float Ts[HWN];                       // y-conv result (25.6 KB)
    __shared__ __align__(16) float Pw[NWAVE][NFP];  // per-wave partials
    __shared__ __align__(16) float PkS[NFP];        // reduced * (5*coef)
    __shared__ float CfS[NFP];

    const int tid  = threadIdx.x;
    const int wid  = tid >> 6;
    const int lane = tid & 63;
    const int bc   = blockIdx.x;       // 0..41
    const int b    = bc / NCH;

    // horizontal 1x10 strip (phases A, F, output): row hr, cols hx..hx+9
    const int hr    = tid >> 3;            // 0..79
    const int hx    = (tid & 7) * NPIX;    // 0,10,..,70
    const int hbase = hr * IMW + hx;
    // vertical 10x1 strip (phase B): col vx, rows vyb..vyb+9
    const int vx  = tid % IMW;
    const int vyb = (tid / IMW) * NPIX;

    const float* predp = pred + (size_t)bc * HWN;
    const float* imgp  = img  + (size_t)b * 3 * HWN;
    float*       outp  = out  + (size_t)bc * HWN;

    // one-time: 5 * Taylor/multinomial coefficient per feature (pad = 0)
    if (tid < NFP) {
        float coef = 0.0f;
        if (tid < NF) {
            const float fact[5] = {1.f, 1.f, 2.f, 6.f, 24.f};
            int ar = AR[tid], ag = AG[tid], ab = AB[tid];
            int k = ar + ag + ab;
            float p25 = 1.0f;
            for (int j = 0; j < k; ++j) p25 *= 25.0f;
            coef = 5.0f / (p25 * fact[ar] * fact[ag] * fact[ab]);
        }
        CfS[tid] = coef;
    }

    // persistent per-pixel state on the horizontal strip
    float qv[NPIX], ev[NPIX];
    #pragma unroll
    for (int j = 0; j < NPIX; ++j) {
        int i = hbase + j;
        float r  = imgp[i];
        float g  = imgp[HWN + i];
        float bb = imgp[2 * HWN + i];
        ev[j] = expf(-(r * r + g * g + bb * bb) * 0.02f);
        float p = predp[i];
        qv[j] = p;
        Qs[i] = p;
    }
    __syncthreads();

    for (int it = 0; it < NITER; ++it) {
        // ---- A: bilateral projection partials, flat static-index loop ----
        float pacc[NFP];
        #pragma unroll
        for (int f = 0; f < NFP; ++f) pacc[f] = 0.0f;

        #pragma unroll
        for (int j = 0; j < NPIX; ++j) {
            int i = hbase + j;
            float r  = imgp[i];
            float g  = imgp[HWN + i];
            float bb = imgp[2 * HWN + i];
            float rp[5], gp[5], bp[5];
            rp[0] = 1.f; gp[0] = 1.f; bp[0] = 1.f;
            #pragma unroll
            for (int k = 1; k < 5; ++k) {
                rp[k] = rp[k-1] * r; gp[k] = gp[k-1] * g; bp[k] = bp[k-1] * bb;
            }
            float qe = qv[j] * ev[j];
            #pragma unroll
            for (int f = 0; f < NF; ++f)   // AR[f] etc. fold to constants
                pacc[f] += qe * rp[AR[f]] * gp[AG[f]] * bp[AB[f]];
        }

        // ---- C: DPP wave-reduce (VALU pipe); lane 63 writes float4 groups ----
        // (placed before B so pacc dies before the conv window registers live)
        #pragma unroll
        for (int f0 = 0; f0 < NFP; f0 += 4) {
            float4 wv4;
            wv4.x = wave_red_sum(pacc[f0 + 0]);
            wv4.y = wave_red_sum(pacc[f0 + 1]);
            wv4.z = wave_red_sum(pacc[f0 + 2]);
            wv4.w = wave_red_sum(pacc[f0 + 3]);
            if (lane == 63) *(float4*)&Pw[wid][f0] = wv4;
        }

        // ---- B: y-conv, vertical strip, register sliding window ----
        {
            float wv[WLEN];
            #pragma unroll
            for (int m = 0; m < WLEN; ++m) {
                int yy = vyb - RAD + m;
                int yc = min(max(yy, 0), IMW - 1);
                float msk = ((unsigned)yy < (unsigned)IMW) ? 1.0f : 0.0f;
                wv[m] = Qs[yc * IMW + vx] * msk;   // branchless clamped load
            }
            #pragma unroll
            for (int k = 0; k < NPIX; ++k) {
                float s = 0.0f;
                #pragma unroll
                for (int j = 0; j < NTAP; ++j) s += wv[k + j] * TK[j];
                Ts[(vyb + k) * IMW + vx] = s;
            }
        }
        __syncthreads();   // Pw ready, Ts ready

        // ---- D: cross-wave reduce + fold 5*coef ----
        if (tid < NFP) {
            float s = 0.0f;
            #pragma unroll
            for (int w = 0; w < NWAVE; ++w) s += Pw[w][tid];
            PkS[tid] = s * CfS[tid];
        }
        __syncthreads();   // PkS ready

        // ---- F: x-conv (register window) + bilateral apply + sigmoid ----
        float sp[NPIX];
        {
            float wv[WLEN];
            #pragma unroll
            for (int m = 0; m < WLEN; ++m) {
                int xx = hx - RAD + m;
                int xc = min(max(xx, 0), IMW - 1);
                float msk = ((unsigned)xx < (unsigned)IMW) ? 1.0f : 0.0f;
                wv[m] = Ts[hr * IMW + xc] * msk;
            }
            #pragma unroll
            for (int k = 0; k < NPIX; ++k) {
                float s = 0.0f;
                #pragma unroll
                for (int j = 0; j < NTAP; ++j) s += wv[k + j] * TK[j];
                sp[k] = s;
            }
        }
        float pk[NFP];
        {
            const float4* p4 = (const float4*)PkS;   // uniform-address broadcast
            #pragma unroll
            for (int k = 0; k < NFP / 4; ++k) {
                float4 t = p4[k];
                pk[4*k+0] = t.x; pk[4*k+1] = t.y; pk[4*k+2] = t.z; pk[4*k+3] = t.w;
            }
        }
        #pragma unroll
        for (int j = 0; j < NPIX; ++j) {
            int i = hbase + j;
            float r  = imgp[i];
            float g  = imgp[HWN + i];
            float bb = imgp[2 * HWN + i];
            float rp[5], gp[5], bp[5];
            rp[0] = 1.f; gp[0] = 1.f; bp[0] = 1.f;
            #pragma unroll
            for (int k = 1; k < 5; ++k) {
                rp[k] = rp[k-1] * r; gp[k] = gp[k-1] * g; bp[k] = bp[k-1] * bb;
            }
            float bi = 0.0f;
            #pragma unroll
            for (int f = 0; f < NF; ++f)   // static indices; ev factored out
                bi += pk[f] * rp[AR[f]] * gp[AG[f]] * bp[AB[f]];
            bi *= ev[j];
            float x = predp[i] - 3.0f * sp[j] - bi;
            float q = 1.0f / (1.0f + expf(-x));
            qv[j] = q;
            Qs[i] = q;
        }
        __syncthreads();   // Qs stable for next B; Ts fully consumed
    }

    #pragma unroll
    for (int j = 0; j < NPIX; ++j) outp[hbase + j] = qv[j];
}

extern "C" void kernel_launch(void* const* d_in, const int* in_sizes, int n_in,
                              void* d_out, int out_size, void* d_ws, size_t ws_size,
                              hipStream_t stream) {
    const float* pred = (const float*)d_in[0];   // [2,21,80,80]
    const float* img  = (const float*)d_in[1];   // [2,3,80,80]
    float* out = (float*)d_out;                  // [2,21,80,80]
    (void)in_sizes; (void)n_in; (void)d_ws; (void)ws_size; (void)out_size;

    crf_fused<<<dim3(2 * NCH), dim3(NTH), 0, stream>>>(pred, img, out);
}